// Round 1
// baseline (3409.571 us; speedup 1.0000x reference)
//
#include <hip/hip_runtime.h>
#include <hip/hip_bf16.h>

#define B_    2
#define S_    2048
#define HID_  2048
#define H_    16
#define KVH_  4
#define D_    128
#define M_    (B_*S_)      // 4096
#define GRP_  (H_/KVH_)    // 4

// ---------------- GEMM tiling (shared by both projection kernels) ----------
#define BM 64
#define BN 64
#define BK 16

// ============ Kernel 1: Y = X @ [Wq | Wk | Wv], RoPE on Q,K, bf16 out ======
__global__ __launch_bounds__(256)
void qkv_rope_kernel(const float* __restrict__ x,      // [4096,2048]
                     const float* __restrict__ freqs,  // [2048,64,2] (cos,sin)
                     const float* __restrict__ wq,     // [2048,2048]
                     const float* __restrict__ wk,     // [2048,512]
                     const float* __restrict__ wv,     // [2048,512]
                     __hip_bfloat16* __restrict__ qo,  // [4096,2048]
                     __hip_bfloat16* __restrict__ ko,  // [4096,512]
                     __hip_bfloat16* __restrict__ vo)  // [4096,512]
{
    __shared__ float As[BM][BK+1];
    __shared__ float Bs[BK][BN+1];

    const int tid = threadIdx.x;
    const int tx = tid & 15, ty = tid >> 4;
    const int row0  = blockIdx.y * BM;
    const int gcol0 = blockIdx.x * BN;   // 0..3071, region-uniform per block

    const float* wb; int wld; int ccol0;
    if (gcol0 < 2048)      { wb = wq; wld = 2048; ccol0 = gcol0; }
    else if (gcol0 < 2560) { wb = wk; wld = 512;  ccol0 = gcol0 - 2048; }
    else                   { wb = wv; wld = 512;  ccol0 = gcol0 - 2560; }

    float acc[4][4] = {};

    for (int k0 = 0; k0 < HID_; k0 += BK) {
        for (int i = tid; i < BM*BK; i += 256) {
            int r = i >> 4, c = i & 15;
            As[r][c] = x[(size_t)(row0 + r)*HID_ + k0 + c];
        }
        for (int i = tid; i < BK*BN; i += 256) {
            int r = i >> 6, c = i & 63;
            Bs[r][c] = wb[(size_t)(k0 + r)*wld + ccol0 + c];
        }
        __syncthreads();
        #pragma unroll
        for (int kk = 0; kk < BK; ++kk) {
            float a[4], b[4];
            #pragma unroll
            for (int i=0;i<4;i++) a[i] = As[ty*4+i][kk];
            #pragma unroll
            for (int j=0;j<4;j++) b[j] = Bs[kk][tx*4+j];
            #pragma unroll
            for (int i=0;i<4;i++)
                #pragma unroll
                for (int j=0;j<4;j++)
                    acc[i][j] += a[i]*b[j];
        }
        __syncthreads();
    }

    const int m0 = row0 + ty*4;
    const int c0 = gcol0 + tx*4;      // even → RoPE pairs stay inside thread
    if (gcol0 < 2560) {               // Q or K region: apply RoPE
        #pragma unroll
        for (int i=0;i<4;i++) {
            int m = m0 + i;
            int s = m & (S_-1);
            #pragma unroll
            for (int jp=0;jp<2;jp++) {
                int c = c0 + jp*2;          // global col (even)
                int d = c & (D_-1);         // within-head dim (even)
                // freqs_cis[s, d/2, 0/1] flat = s*128 + d (+1 for sin), d even
                float cs = freqs[(size_t)s*D_ + d];
                float sn = freqs[(size_t)s*D_ + d + 1];
                float xr = acc[i][jp*2], xi = acc[i][jp*2+1];
                float orr = xr*cs - xi*sn;
                float oi  = xr*sn + xi*cs;
                if (gcol0 < 2048) {
                    qo[(size_t)m*2048 + c]     = __float2bfloat16(orr);
                    qo[(size_t)m*2048 + c + 1] = __float2bfloat16(oi);
                } else {
                    int cc = c - 2048;
                    ko[(size_t)m*512 + cc]     = __float2bfloat16(orr);
                    ko[(size_t)m*512 + cc + 1] = __float2bfloat16(oi);
                }
            }
        }
    } else {                           // V region: plain store
        #pragma unroll
        for (int i=0;i<4;i++) {
            int m = m0 + i;
            #pragma unroll
            for (int j=0;j<4;j++)
                vo[(size_t)m*512 + (c0 - 2560) + j] = __float2bfloat16(acc[i][j]);
        }
    }
}

// ============ Kernel 2: flash-style causal attention =======================
// grid (32 q-tiles, 16 heads, 2 batch), 256 threads.
// Row pad 128->136 bf16: row stride 272B breaks the 16-way bank conflict a
// 256B stride would cause on the K^T column reads.
#define QPAD 136
__global__ __launch_bounds__(256)
void attn_kernel(const __hip_bfloat16* __restrict__ qws,  // [4096,2048]
                 const __hip_bfloat16* __restrict__ kws,  // [4096,512]
                 const __hip_bfloat16* __restrict__ vws,  // [4096,512]
                 __hip_bfloat16* __restrict__ aows)       // [4096,2048]
{
    __shared__ __align__(16) __hip_bfloat16 Qs[64][QPAD];
    __shared__ __align__(16) __hip_bfloat16 Ks[64][QPAD];
    __shared__ __align__(16) __hip_bfloat16 Vs[64][QPAD];
    __shared__ float Ps[64][65];

    const int tid = threadIdx.x;
    const int tx = tid & 15, ty = tid >> 4;
    const int qt = blockIdx.x;         // 0..31
    const int h  = blockIdx.y;         // 0..15
    const int b  = blockIdx.z;         // 0..1
    const int hk = h >> 2;             // GQA: q-head h -> kv-head h/4
    const int q0 = qt * 64;
    const float scale = 0.08838834764831845f;  // 1/sqrt(128)

    {   // load Q tile (64 rows x 128 bf16) as 16B vectors
        const __hip_bfloat16* qbase = qws + (size_t)(b*S_ + q0)*2048 + h*D_;
        for (int i = tid; i < 64*16; i += 256) {
            int r = i >> 4, c4 = i & 15;
            ((uint4*)&Qs[r][0])[c4] = ((const uint4*)(qbase + (size_t)r*2048))[c4];
        }
    }

    float m_i[4], l_i[4], oacc[4][8];
    #pragma unroll
    for (int i=0;i<4;i++){ m_i[i]=-1e30f; l_i[i]=0.f;
        #pragma unroll
        for (int c=0;c<8;c++) oacc[i][c]=0.f; }

    const int r0  = ty*4;   // 4 q-rows per thread
    const int kc0 = tx*4;   // 4 score cols per thread
    const int oc0 = tx*8;   // 8 output cols per thread

    for (int kt = 0; kt <= qt; ++kt) {
        __syncthreads();   // prev PV readers done before Ks/Vs overwrite
        const __hip_bfloat16* kbase = kws + (size_t)(b*S_ + kt*64)*512 + hk*D_;
        const __hip_bfloat16* vbase = vws + (size_t)(b*S_ + kt*64)*512 + hk*D_;
        for (int i = tid; i < 64*16; i += 256) {
            int r = i >> 4, c4 = i & 15;
            ((uint4*)&Ks[r][0])[c4] = ((const uint4*)(kbase + (size_t)r*512))[c4];
            ((uint4*)&Vs[r][0])[c4] = ((const uint4*)(vbase + (size_t)r*512))[c4];
        }
        __syncthreads();

        // scores: s[i][j] = Q[r0+i] . K[kc0+j]
        float sc[4][4] = {};
        for (int d = 0; d < D_; d += 2) {
            float2 qv[4], kv[4];
            #pragma unroll
            for (int i=0;i<4;i++)
                qv[i] = __bfloat1622float2(*(__hip_bfloat162*)&Qs[r0+i][d]);
            #pragma unroll
            for (int j=0;j<4;j++)
                kv[j] = __bfloat1622float2(*(__hip_bfloat162*)&Ks[kc0+j][d]);
            #pragma unroll
            for (int i=0;i<4;i++)
                #pragma unroll
                for (int j=0;j<4;j++)
                    sc[i][j] += qv[i].x*kv[j].x + qv[i].y*kv[j].y;
        }

        // mask + scale + online softmax (16 lanes of same ty own one row set)
        #pragma unroll
        for (int i=0;i<4;i++) {
            int sq = q0 + r0 + i;
            float rmax = -1e30f;
            #pragma unroll
            for (int j=0;j<4;j++) {
                int sk = kt*64 + kc0 + j;
                float v = sc[i][j]*scale;
                v = (sk <= sq) ? v : -1e30f;
                sc[i][j] = v;
                rmax = fmaxf(rmax, v);
            }
            #pragma unroll
            for (int off=1; off<16; off<<=1)
                rmax = fmaxf(rmax, __shfl_xor(rmax, off, 16));
            float mn = fmaxf(m_i[i], rmax);
            float alpha = __expf(m_i[i] - mn);
            float rsum = 0.f;
            #pragma unroll
            for (int j=0;j<4;j++) {
                float p = __expf(sc[i][j] - mn);
                Ps[r0+i][kc0+j] = p;
                rsum += p;
            }
            #pragma unroll
            for (int off=1; off<16; off<<=1)
                rsum += __shfl_xor(rsum, off, 16);
            l_i[i] = l_i[i]*alpha + rsum;
            m_i[i] = mn;
            #pragma unroll
            for (int c=0;c<8;c++) oacc[i][c] *= alpha;
        }
        __syncthreads();

        // PV: oacc[i][c] += sum_k P[r0+i][k] * V[k][oc0+c]
        for (int k = 0; k < 64; ++k) {
            float p4[4];
            #pragma unroll
            for (int i=0;i<4;i++) p4[i] = Ps[r0+i][k];
            float v8[8];
            #pragma unroll
            for (int c=0;c<4;c++) {
                float2 f = __bfloat1622float2(*(__hip_bfloat162*)&Vs[k][oc0 + c*2]);
                v8[c*2] = f.x; v8[c*2+1] = f.y;
            }
            #pragma unroll
            for (int i=0;i<4;i++)
                #pragma unroll
                for (int c=0;c<8;c++)
                    oacc[i][c] += p4[i]*v8[c];
        }
    }

    #pragma unroll
    for (int i=0;i<4;i++) {
        float inv = 1.f / l_i[i];
        size_t base = (size_t)(b*S_ + q0 + r0 + i)*2048 + h*D_ + oc0;
        #pragma unroll
        for (int c=0;c<8;c++)
            aows[base + c] = __float2bfloat16(oacc[i][c] * inv);
    }
}

// ============ Kernel 3: out = AO @ Wo ======================================
__global__ __launch_bounds__(256)
void out_gemm_kernel(const __hip_bfloat16* __restrict__ a,  // [4096,2048]
                     const float* __restrict__ wo,          // [2048,2048]
                     float* __restrict__ out)               // [4096,2048]
{
    __shared__ float As[BM][BK+1];
    __shared__ float Bs[BK][BN+1];

    const int tid = threadIdx.x;
    const int tx = tid & 15, ty = tid >> 4;
    const int row0 = blockIdx.y * BM;
    const int col0 = blockIdx.x * BN;

    float acc[4][4] = {};

    for (int k0 = 0; k0 < HID_; k0 += BK) {
        for (int i = tid; i < BM*BK; i += 256) {
            int r = i >> 4, c = i & 15;
            As[r][c] = __bfloat162float(a[(size_t)(row0 + r)*HID_ + k0 + c]);
        }
        for (int i = tid; i < BK*BN; i += 256) {
            int r = i >> 6, c = i & 63;
            Bs[r][c] = wo[(size_t)(k0 + r)*HID_ + col0 + c];
        }
        __syncthreads();
        #pragma unroll
        for (int kk = 0; kk < BK; ++kk) {
            float av[4], bv[4];
            #pragma unroll
            for (int i=0;i<4;i++) av[i] = As[ty*4+i][kk];
            #pragma unroll
            for (int j=0;j<4;j++) bv[j] = Bs[kk][tx*4+j];
            #pragma unroll
            for (int i=0;i<4;i++)
                #pragma unroll
                for (int j=0;j<4;j++)
                    acc[i][j] += av[i]*bv[j];
        }
        __syncthreads();
    }

    #pragma unroll
    for (int i=0;i<4;i++) {
        size_t m = row0 + ty*4 + i;
        #pragma unroll
        for (int j=0;j<4;j++)
            out[m*HID_ + col0 + tx*4 + j] = acc[i][j];
    }
}

// ============ launch =======================================================
extern "C" void kernel_launch(void* const* d_in, const int* in_sizes, int n_in,
                              void* d_out, int out_size, void* d_ws, size_t ws_size,
                              hipStream_t stream) {
    const float* x     = (const float*)d_in[0];
    const float* freqs = (const float*)d_in[1];
    const float* wq    = (const float*)d_in[2];
    const float* wk    = (const float*)d_in[3];
    const float* wv    = (const float*)d_in[4];
    const float* wo    = (const float*)d_in[5];
    float* out = (float*)d_out;

    // workspace: Q bf16 16MB | K bf16 4MB | V bf16 4MB | AO bf16 16MB (=40MB)
    const size_t QB  = (size_t)M_ * 2048 * sizeof(__hip_bfloat16);
    const size_t KVB = (size_t)M_ * 512  * sizeof(__hip_bfloat16);
    char* ws = (char*)d_ws;
    __hip_bfloat16* qws  = (__hip_bfloat16*)(ws);
    __hip_bfloat16* kws  = (__hip_bfloat16*)(ws + QB);
    __hip_bfloat16* vws  = (__hip_bfloat16*)(ws + QB + KVB);
    __hip_bfloat16* aows = (__hip_bfloat16*)(ws + QB + 2*KVB);

    dim3 blk(256);
    dim3 g1(3072/BN, M_/BM);            // 48 x 64
    qkv_rope_kernel<<<g1, blk, 0, stream>>>(x, freqs, wq, wk, wv, qws, kws, vws);

    dim3 g2(S_/64, H_, B_);             // 32 x 16 x 2
    attn_kernel<<<g2, blk, 0, stream>>>(qws, kws, vws, aows);

    dim3 g3(HID_/BN, M_/BM);            // 32 x 64
    out_gemm_kernel<<<g3, blk, 0, stream>>>(aows, wo, out);
}

// Round 2
// 440.849 us; speedup vs baseline: 7.7341x; 7.7341x over previous
//
#include <hip/hip_runtime.h>
#include <hip/hip_bf16.h>

#define B_   2
#define S_   2048
#define HID_ 2048
#define H_   16
#define KVH_ 4
#define D_   128
#define M_   4096
#define NQKV 3072

typedef __attribute__((ext_vector_type(8))) short bf16x8;   // 8 bf16 = 4 VGPR
typedef __attribute__((ext_vector_type(4))) float f32x4;

__device__ __forceinline__ unsigned short f2b(float f) {
    __hip_bfloat16 h = __float2bfloat16(f);
    return *reinterpret_cast<unsigned short*>(&h);
}
__device__ __forceinline__ float b2f(unsigned short u) {
    __hip_bfloat16 h;
    *reinterpret_cast<unsigned short*>(&h) = u;
    return __bfloat162float(h);
}

// ---------- convert x: fp32 -> bf16, vectorized ----------------------------
__global__ __launch_bounds__(256)
void convert_x(const float* __restrict__ x, unsigned short* __restrict__ xb) {
    int i = (blockIdx.x * 256 + threadIdx.x) * 4;
    float4 v = *(const float4*)(x + i);
    ushort4 o;
    o.x = f2b(v.x); o.y = f2b(v.y); o.z = f2b(v.z); o.w = f2b(v.w);
    *(ushort4*)(xb + i) = o;
}

// ---------- convert + transpose weight: w[2048][N] fp32 -> wt[(nbase+n)][k] bf16
__global__ __launch_bounds__(256)
void convert_w_t(const float* __restrict__ w, int N,
                 unsigned short* __restrict__ wt, int nbase) {
    __shared__ float tile[32][33];
    int tx = threadIdx.x & 31, ty = threadIdx.x >> 5;   // 32 x 8
    int n0 = blockIdx.x * 32, k0 = blockIdx.y * 32;
    #pragma unroll
    for (int j = 0; j < 4; j++)
        tile[ty + j*8][tx] = w[(size_t)(k0 + ty + j*8) * N + n0 + tx];
    __syncthreads();
    #pragma unroll
    for (int j = 0; j < 4; j++)
        wt[(size_t)(nbase + n0 + ty + j*8) * 2048 + k0 + tx] = f2b(tile[tx][ty + j*8]);
}

// ---------- MFMA GEMM: C[M][N] = A[M][2048] * BT[N][2048]^T ----------------
// 128x128 tile, BK=32, 4 waves (2x2 of 64x64), 4x4 MFMA 16x16x32 tiles/wave.
// LDS row stride 40 bf16 (80B): frag reads & staging writes both land 8
// lanes per 4-bank group = the LDS delivery floor (conflict-free).
template<bool BF16OUT>
__global__ __launch_bounds__(256)
void gemm_bt(const unsigned short* __restrict__ A,
             const unsigned short* __restrict__ BT,
             void* __restrict__ Cv, int N) {
    __shared__ unsigned short As[128][40];
    __shared__ unsigned short Bs[128][40];

    int tid  = threadIdx.x;
    int lane = tid & 63, w = tid >> 6;
    int quad = lane >> 4, l15 = lane & 15;
    int row0 = blockIdx.y * 128, col0 = blockIdx.x * 128;
    int wm = (w & 1) * 64, wn = (w >> 1) * 64;

    f32x4 acc[4][4];
    const f32x4 zf = {0.f, 0.f, 0.f, 0.f};
    #pragma unroll
    for (int i = 0; i < 4; i++)
        #pragma unroll
        for (int j = 0; j < 4; j++) acc[i][j] = zf;

    for (int k0 = 0; k0 < 2048; k0 += 32) {
        #pragma unroll
        for (int it = 0; it < 2; it++) {
            int cid = tid + it * 256;
            int r = cid >> 2, c8 = (cid & 3) * 8;
            *(uint4*)&As[r][c8] = *(const uint4*)(A  + (size_t)(row0 + r) * 2048 + k0 + c8);
            *(uint4*)&Bs[r][c8] = *(const uint4*)(BT + (size_t)(col0 + r) * 2048 + k0 + c8);
        }
        __syncthreads();
        bf16x8 af[4], bf[4];
        #pragma unroll
        for (int i = 0; i < 4; i++) af[i] = *(const bf16x8*)&As[wm + i*16 + l15][quad * 8];
        #pragma unroll
        for (int j = 0; j < 4; j++) bf[j] = *(const bf16x8*)&Bs[wn + j*16 + l15][quad * 8];
        #pragma unroll
        for (int i = 0; i < 4; i++)
            #pragma unroll
            for (int j = 0; j < 4; j++)
                acc[i][j] = __builtin_amdgcn_mfma_f32_16x16x32_bf16(af[i], bf[j], acc[i][j], 0, 0, 0);
        __syncthreads();
    }

    // C/D layout: col = lane&15, row = quad*4 + reg  [m89/m91 verified]
    #pragma unroll
    for (int i = 0; i < 4; i++)
        #pragma unroll
        for (int j = 0; j < 4; j++)
            #pragma unroll
            for (int r = 0; r < 4; r++) {
                size_t idx = (size_t)(row0 + wm + i*16 + quad*4 + r) * N + col0 + wn + j*16 + l15;
                if (BF16OUT) ((unsigned short*)Cv)[idx] = f2b(acc[i][j][r]);
                else         ((float*)Cv)[idx] = acc[i][j][r];
            }
}

// ---------- RoPE on Q,K region of qkv buffer (cols 0..2559), in place ------
__global__ __launch_bounds__(256)
void rope_kernel(unsigned short* __restrict__ qkv, const float* __restrict__ freqs) {
    int p = blockIdx.x * 256 + threadIdx.x;     // pair id, 4096*1280 total
    int m = p / 1280;
    int cp = p - m * 1280;
    int col = cp * 2;
    int s = m & (S_ - 1);
    int d = col & (D_ - 1);                     // works for Q (cols<2048) and K (2048..2559)
    unsigned short* ptr = qkv + (size_t)m * NQKV + col;
    ushort2 uv = *(ushort2*)ptr;
    float xr = b2f(uv.x), xi = b2f(uv.y);
    float cs = freqs[s * 128 + d], sn = freqs[s * 128 + d + 1];
    ushort2 ov;
    ov.x = f2b(xr * cs - xi * sn);
    ov.y = f2b(xr * sn + xi * cs);
    *(ushort2*)ptr = ov;
}

// ---------- transpose V region -> vT[(b*512 + kvcol)][s] -------------------
__global__ __launch_bounds__(256)
void v_transpose(const unsigned short* __restrict__ qkv, unsigned short* __restrict__ vT) {
    __shared__ unsigned short tile[32][34];
    int tx = threadIdx.x & 31, ty = threadIdx.x >> 5;
    int s0 = blockIdx.x * 32;      // 64 blocks
    int c0 = blockIdx.y * 32;      // 16 blocks (cv 0..511)
    int b  = blockIdx.z;
    #pragma unroll
    for (int j = 0; j < 4; j++)
        tile[ty + j*8][tx] = qkv[(size_t)(b*2048 + s0 + ty + j*8) * NQKV + 2560 + c0 + tx];
    __syncthreads();
    #pragma unroll
    for (int j = 0; j < 4; j++)
        vT[(size_t)(b*512 + c0 + ty + j*8) * 2048 + s0 + tx] = tile[tx][ty + j*8];
}

// ---------- MFMA flash attention ------------------------------------------
// Block = (q-tile 64, head, batch), 4 waves; wave w owns q-rows w*16..w*16+15.
// S = Q K^T via 16x16x32 MFMA (Q,K K-contiguous in LDS); online softmax in
// C-layout regs (row = quad*4+reg); P -> per-wave LDS (C-layout write,
// A-layout b128 read, m120 transform); PV MFMA against Vt[d][s] tile.
__global__ __launch_bounds__(256)
void attn_mfma(const unsigned short* __restrict__ qkv,
               const unsigned short* __restrict__ vT,
               unsigned short* __restrict__ ao) {
    __shared__ unsigned short Qs[64][136];   // stride 272B: frag reads at floor
    __shared__ unsigned short Ks[64][136];
    __shared__ unsigned short Vt[128][72];   // stride 144B: same
    __shared__ unsigned short Ps[4][16][72];

    int tid  = threadIdx.x;
    int lane = tid & 63, w = tid >> 6;
    int quad = lane >> 4, l15 = lane & 15;
    int qt = blockIdx.x, h = blockIdx.y, b = blockIdx.z;
    int hk = h >> 2;
    int q0 = qt * 64;
    const float scale = 0.08838834764831845f;   // 1/sqrt(128)

    #pragma unroll
    for (int it = 0; it < 4; it++) {
        int cid = tid + it * 256;
        int r = cid >> 4, c8 = (cid & 15) * 8;
        *(uint4*)&Qs[r][c8] = *(const uint4*)(qkv + (size_t)(b*2048 + q0 + r) * NQKV + h*128 + c8);
    }

    f32x4 o_acc[8];
    const f32x4 zf = {0.f, 0.f, 0.f, 0.f};
    #pragma unroll
    for (int jn = 0; jn < 8; jn++) o_acc[jn] = zf;
    float m_i[4], l_i[4];
    #pragma unroll
    for (int r = 0; r < 4; r++) { m_i[r] = -1e30f; l_i[r] = 0.f; }

    for (int kt = 0; kt <= qt; kt++) {
        __syncthreads();                    // prior PV readers done
        #pragma unroll
        for (int it = 0; it < 4; it++) {
            int cid = tid + it * 256;
            int r = cid >> 4, c8 = (cid & 15) * 8;
            *(uint4*)&Ks[r][c8] = *(const uint4*)(qkv + (size_t)(b*2048 + kt*64 + r) * NQKV + 2048 + hk*128 + c8);
            int r2 = cid >> 3, c82 = (cid & 7) * 8;
            *(uint4*)&Vt[r2][c82] = *(const uint4*)(vT + (size_t)(b*512 + hk*128 + r2) * 2048 + kt*64 + c82);
        }
        __syncthreads();

        // ---- S = Q K^T (wave's 16 rows x 64 cols) ----
        bf16x8 aq[4];
        #pragma unroll
        for (int k4 = 0; k4 < 4; k4++)
            aq[k4] = *(const bf16x8*)&Qs[w*16 + l15][k4*32 + quad*8];
        f32x4 s_acc[4];
        #pragma unroll
        for (int j = 0; j < 4; j++) {
            s_acc[j] = zf;
            #pragma unroll
            for (int k4 = 0; k4 < 4; k4++) {
                bf16x8 bk = *(const bf16x8*)&Ks[j*16 + l15][k4*32 + quad*8];
                s_acc[j] = __builtin_amdgcn_mfma_f32_16x16x32_bf16(aq[k4], bk, s_acc[j], 0, 0, 0);
            }
        }

        // ---- mask + scale ----
        float sv[4][4];
        if (kt == qt) {
            #pragma unroll
            for (int j = 0; j < 4; j++)
                #pragma unroll
                for (int r = 0; r < 4; r++) {
                    float v = s_acc[j][r] * scale;
                    sv[j][r] = (j*16 + l15 <= w*16 + quad*4 + r) ? v : -1e30f;
                }
        } else {
            #pragma unroll
            for (int j = 0; j < 4; j++)
                #pragma unroll
                for (int r = 0; r < 4; r++) sv[j][r] = s_acc[j][r] * scale;
        }

        // ---- online softmax (stats per row = quad*4+r, reduce over 16 lanes) ----
        float rsum[4];
        #pragma unroll
        for (int r = 0; r < 4; r++) {
            float rmax = fmaxf(fmaxf(sv[0][r], sv[1][r]), fmaxf(sv[2][r], sv[3][r]));
            #pragma unroll
            for (int off = 1; off < 16; off <<= 1)
                rmax = fmaxf(rmax, __shfl_xor(rmax, off));
            float mnew = fmaxf(m_i[r], rmax);
            float alpha = __expf(m_i[r] - mnew);
            float rs = 0.f;
            #pragma unroll
            for (int j = 0; j < 4; j++) {
                float p = __expf(sv[j][r] - mnew);
                Ps[w][quad*4 + r][j*16 + l15] = f2b(p);
                rs += p;
            }
            #pragma unroll
            for (int off = 1; off < 16; off <<= 1)
                rs += __shfl_xor(rs, off);
            rsum[r] = rs;
            l_i[r] = l_i[r] * alpha + rs;
            m_i[r] = mnew;
            #pragma unroll
            for (int jn = 0; jn < 8; jn++) o_acc[jn][r] *= alpha;
        }
        (void)rsum;

        // ---- PV: O += P * V  (A-frag from Ps, B-frag from Vt) ----
        bf16x8 ap0 = *(const bf16x8*)&Ps[w][l15][quad*8];
        bf16x8 ap1 = *(const bf16x8*)&Ps[w][l15][32 + quad*8];
        #pragma unroll
        for (int jn = 0; jn < 8; jn++) {
            bf16x8 bv0 = *(const bf16x8*)&Vt[jn*16 + l15][quad*8];
            bf16x8 bv1 = *(const bf16x8*)&Vt[jn*16 + l15][32 + quad*8];
            o_acc[jn] = __builtin_amdgcn_mfma_f32_16x16x32_bf16(ap0, bv0, o_acc[jn], 0, 0, 0);
            o_acc[jn] = __builtin_amdgcn_mfma_f32_16x16x32_bf16(ap1, bv1, o_acc[jn], 0, 0, 0);
        }
    }

    #pragma unroll
    for (int r = 0; r < 4; r++) {
        float inv = 1.f / l_i[r];
        size_t base = (size_t)(b*2048 + q0 + w*16 + quad*4 + r) * 2048 + h*128;
        #pragma unroll
        for (int jn = 0; jn < 8; jn++)
            ao[base + jn*16 + l15] = f2b(o_acc[jn][r] * inv);
    }
}

// ---------- launch ---------------------------------------------------------
extern "C" void kernel_launch(void* const* d_in, const int* in_sizes, int n_in,
                              void* d_out, int out_size, void* d_ws, size_t ws_size,
                              hipStream_t stream) {
    const float* x     = (const float*)d_in[0];
    const float* freqs = (const float*)d_in[1];
    const float* wq    = (const float*)d_in[2];
    const float* wk    = (const float*)d_in[3];
    const float* wv    = (const float*)d_in[4];
    const float* wo    = (const float*)d_in[5];
    float* out = (float*)d_out;

    char* ws = (char*)d_ws;
    // 64MB total; ao aliases xbf (xbf dead after GEMM1, ao written after it)
    unsigned short* xbf    = (unsigned short*)(ws);                  // 16MB
    unsigned short* aobuf  = (unsigned short*)(ws);                  // alias
    unsigned short* wqkvT  = (unsigned short*)(ws + (16u<<20));      // 12MB
    unsigned short* woT    = (unsigned short*)(ws + (28u<<20));      // 8MB
    unsigned short* qkvbuf = (unsigned short*)(ws + (36u<<20));      // 24MB
    unsigned short* vTbuf  = (unsigned short*)(ws + (60u<<20));      // 4MB

    dim3 blk(256);
    convert_x<<<8192, blk, 0, stream>>>(x, xbf);
    convert_w_t<<<dim3(64, 64), blk, 0, stream>>>(wq, 2048, wqkvT, 0);
    convert_w_t<<<dim3(16, 64), blk, 0, stream>>>(wk,  512, wqkvT, 2048);
    convert_w_t<<<dim3(16, 64), blk, 0, stream>>>(wv,  512, wqkvT, 2560);
    convert_w_t<<<dim3(64, 64), blk, 0, stream>>>(wo, 2048, woT, 0);

    gemm_bt<true><<<dim3(NQKV/128, M_/128), blk, 0, stream>>>(xbf, wqkvT, qkvbuf, NQKV);
    rope_kernel<<<20480, blk, 0, stream>>>(qkvbuf, freqs);
    v_transpose<<<dim3(64, 16, 2), blk, 0, stream>>>(qkvbuf, vTbuf);
    attn_mfma<<<dim3(32, 16, 2), blk, 0, stream>>>(qkvbuf, vTbuf, aobuf);
    gemm_bt<false><<<dim3(2048/128, M_/128), blk, 0, stream>>>(aobuf, woT, out, 2048);
}